// Round 10
// baseline (856.135 us; speedup 1.0000x reference)
//
#include <hip/hip_runtime.h>
#include <hip/hip_bf16.h>
#include <math.h>

#define BATCH 64
#define SEQ   256
#define CH    384
#define NHEAD 8
#define HD    48
#define DEPTH 6
#define NTOK  (BATCH*SEQ)   // 16384
#define C3    (3*CH)        // 1152
#define LN_EPS 1e-5f
#define ATT_SCALE 0.14433756729740643f  // 48^-0.5

typedef __attribute__((ext_vector_type(8)))  short bf16x8;
typedef __attribute__((ext_vector_type(4)))  float f32x4;
typedef __attribute__((ext_vector_type(16))) float f32x16;

__device__ __forceinline__ ushort f2bf(float f) {
    __hip_bfloat16 h = __float2bfloat16(f);
    return *(ushort*)&h;
}
__device__ __forceinline__ float bfu2f(ushort u) {
    uint t = ((uint)u) << 16;
    union { uint u; float f; } c; c.u = t; return c.f;
}
__device__ __forceinline__ uint pk2(float a, float b) {
    return (uint)f2bf(a) | ((uint)f2bf(b) << 16);
}

#define AS1(p) ((const __attribute__((address_space(1))) void*)(p))
#define AS3(p) ((__attribute__((address_space(3))) void*)(uintptr_t)(p))
#define WAITVMC(N) asm volatile("s_waitcnt vmcnt(" #N ")" ::: "memory")
#define TAILSYNC() do { \
    asm volatile("s_waitcnt lgkmcnt(0)" ::: "memory"); \
    __builtin_amdgcn_sched_barrier(0); \
    __builtin_amdgcn_s_barrier(); } while (0)

// ---------------- zero stat accumulators ----------------
__global__ void zero_kernel(float4* __restrict__ p) {
    p[blockIdx.x*256 + threadIdx.x] = float4{0.f,0.f,0.f,0.f};
}

// ---------------- fp32 -> bf16 bulk convert ----------------
__global__ void f2bf4_kernel(const float* __restrict__ in, ushort* __restrict__ out) {
    int i = (blockIdx.x*256 + threadIdx.x)*4;
    float4 v = *(const float4*)(in + i);
    ushort4 o;
    o.x = f2bf(v.x); o.y = f2bf(v.y); o.z = f2bf(v.z); o.w = f2bf(v.w);
    *(ushort4*)(out + i) = o;
}

// ---------------- rope cos/sin table ----------------
__global__ void rope_table_kernel(float2* __restrict__ tbl) {
    int pos = threadIdx.x;
    for (int j = 0; j < 24; ++j) {
        float freq = exp2f(-(float)j * (13.287712379549449f / 24.0f));
        float ang = (float)pos * freq;
        float s, c;
        sincosf(ang, &s, &c);
        tbl[pos*24 + j] = make_float2(c, s);
    }
}

// ---------------- embed stage 1 -> bf16 ----------------
__global__ void embed1_kernel(const float* __restrict__ x, const float* __restrict__ w1,
                              const float* __restrict__ b1, ushort* __restrict__ out) {
    int idx = blockIdx.x*256 + threadIdx.x;
    int m = idx / CH, c = idx - m*CH;
    float v = x[m*2]*w1[c*2] + x[m*2+1]*w1[c*2+1] + b1[c];
    out[idx] = f2bf(fmaxf(v, 0.f));
}

// ---------------- LN-affine weight prep: W' = gam .* W (bf16), uv = {u, v(+bias)} ----------------
__global__ __launch_bounds__(256) void prep_kernel(
        const float* __restrict__ Wsrc, const float* __restrict__ gam,
        const float* __restrict__ bet, const float* __restrict__ bias,
        int npl, ushort* __restrict__ Wdst, float2* __restrict__ uvout) {
    int rr   = blockIdx.x*4 + (threadIdx.x >> 6);
    int lane = threadIdx.x & 63;
    int layer = rr / npl;
    const float* wp = Wsrc + (size_t)rr*CH;
    const float* gp = gam + layer*CH;
    const float* bp = bet + layer*CH;
    float u = 0.f, vv = 0.f;
    if (lane < 48) {
        int c0 = lane*8;
        float w8[8];
        *(float4*)&w8[0] = *(const float4*)(wp + c0);
        *(float4*)&w8[4] = *(const float4*)(wp + c0 + 4);
        union { ushort us[8]; bf16x8 v; } o;
        #pragma unroll
        for (int j = 0; j < 8; ++j) {
            float wg = w8[j] * gp[c0+j];
            u  += wg;
            vv += bp[c0+j] * w8[j];
            o.us[j] = f2bf(wg);
        }
        *(bf16x8*)(Wdst + (size_t)rr*CH + c0) = o.v;
    }
    #pragma unroll
    for (int o = 1; o < 64; o <<= 1) { u += __shfl_xor(u, o); vv += __shfl_xor(vv, o); }
    if (lane == 0) {
        if (bias) vv += bias[rr];
        uvout[rr] = make_float2(u, vv);
    }
}

// ---------------- uniform bf16 MFMA NT-GEMM: BM=128,BN=128,BK=64, ring-2, T2-swizzled ----------------
// LNAFF: out = inv_m*(S - mu_m*u_n) + v_n [relu]; mu/inv from sbr sums; QKV: V-blocks -> vtbuf
// else : out = S + bias [+resid] -> h fp32 + hbf bf16; row (sum,sumsq) atomics into sbw
template<bool LNAFF, bool RELU, bool RESID, bool QKV>
__global__ __launch_bounds__(256) void gemm_kernel(
        const ushort* __restrict__ A,      // [M][CH] bf16
        const ushort* __restrict__ W,      // [N][CH] bf16 (W' for LNAFF)
        const float*  __restrict__ bias,   // [N] (non-LNAFF)
        const float2* __restrict__ uv,     // [N] (LNAFF)
        const float2* __restrict__ sbr,    // [M] row sums in (LNAFF)
        const float*  __restrict__ resid,  // [M][CH] fp32 (RESID)
        float*  __restrict__ hout,         // fp32 out (non-LNAFF)
        ushort* __restrict__ bout,         // bf16 out
        int ldo,
        float2* __restrict__ sbw,          // [M] row sums out (non-LNAFF, may be null)
        ushort* __restrict__ vtbuf) {      // [B*H*HD][SEQ] transposed V (QKV)
    __shared__ __align__(16) ushort As[2][8192];
    __shared__ __align__(16) ushort Bs[2][8192];
    const int tid  = threadIdx.x;
    const int lane = tid & 63;
    const int w    = tid >> 6;
    const int l15  = lane & 15;
    const int g    = lane >> 4;
    const int wr   = (w >> 1) * 64;
    const int wc   = (w & 1) * 64;
    const int m0   = blockIdx.y * 128;
    const int n0   = blockIdx.x * 128;

    const int srow = lane >> 3;
    const int scol = ((lane & 7) ^ srow) * 8;
    auto stage = [&](int pb, int t) {
        int k0 = t*64;
        #pragma unroll
        for (int c = 0; c < 8; ++c) {
            int chunk = w + c*4;
            if (chunk < 16) {
                const ushort* gp = A + (size_t)(m0 + chunk*8 + srow)*CH + k0 + scol;
                __builtin_amdgcn_global_load_lds(AS1(gp), AS3(&As[pb][chunk*512]), 16, 0, 0);
            } else {
                const ushort* gp = W + (size_t)(n0 + (chunk-16)*8 + srow)*CH + k0 + scol;
                __builtin_amdgcn_global_load_lds(AS1(gp), AS3(&Bs[pb][(chunk-16)*512]), 16, 0, 0);
            }
        }
    };

    f32x4 acc[4][4] = {};
    const int xm = (l15 & 7) << 4;

    stage(0, 0);
    for (int t = 0; t < 6; ++t) {
        if (t + 1 < 6) stage((t+1)&1, t+1);
        if (t < 5) { WAITVMC(8); } else { WAITVMC(0); }
        __builtin_amdgcn_s_barrier();
        const int pb = t & 1;
        #pragma unroll
        for (int kk = 0; kk < 2; ++kk) {
            bf16x8 a[4], b[4];
            #pragma unroll
            for (int i = 0; i < 4; ++i)
                a[i] = *(const bf16x8*)((const char*)As[pb]
                        + (wr + i*16 + l15)*128 + ((kk*64 + 16*g) ^ xm));
            #pragma unroll
            for (int j = 0; j < 4; ++j)
                b[j] = *(const bf16x8*)((const char*)Bs[pb]
                        + (wc + j*16 + l15)*128 + ((kk*64 + 16*g) ^ xm));
            #pragma unroll
            for (int i = 0; i < 4; ++i)
                #pragma unroll
                for (int j = 0; j < 4; ++j)
                    acc[i][j] = __builtin_amdgcn_mfma_f32_16x16x32_bf16(a[i], b[j], acc[i][j], 0, 0, 0);
        }
        TAILSYNC();
    }

    const int cbase = n0 + wc + l15;
    const int rbase = m0 + wr + g*4;
    if (LNAFF) {
        float2 uvv[4];
        #pragma unroll
        for (int j = 0; j < 4; ++j) uvv[j] = uv[cbase + j*16];
        const bool isV = QKV && (n0 >= 2*CH);
        int hj[4], dj[4];
        if (isV) {
            #pragma unroll
            for (int j = 0; j < 4; ++j) {
                int nn = cbase + j*16 - 2*CH;
                hj[j] = nn / HD; dj[j] = nn - hj[j]*HD;
            }
        }
        #pragma unroll
        for (int i = 0; i < 4; ++i) {
            float muv[4], invv[4];
            #pragma unroll
            for (int r = 0; r < 4; ++r) {
                float2 s2 = sbr[rbase + i*16 + r];
                float mu = s2.x * (1.0f/CH);
                float var = s2.y * (1.0f/CH) - mu*mu;
                muv[r] = mu; invv[r] = rsqrtf(var + LN_EPS);
            }
            if (isV) {
                int bb   = rbase >> 8;                 // batch (constant per block)
                int seq0 = (rbase + i*16) & 255;
                #pragma unroll
                for (int j = 0; j < 4; ++j) {
                    float vr[4];
                    #pragma unroll
                    for (int r = 0; r < 4; ++r)
                        vr[r] = invv[r]*(acc[i][j][r] - muv[r]*uvv[j].x) + uvv[j].y;
                    uint2 val;
                    val.x = pk2(vr[0], vr[1]);
                    val.y = pk2(vr[2], vr[3]);
                    *(uint2*)(vtbuf + (((size_t)bb*NHEAD + hj[j])*HD + dj[j])*SEQ + seq0) = val;
                }
            } else {
                #pragma unroll
                for (int r = 0; r < 4; ++r) {
                    int m = rbase + i*16 + r;
                    #pragma unroll
                    for (int j = 0; j < 4; ++j) {
                        float v = invv[r]*(acc[i][j][r] - muv[r]*uvv[j].x) + uvv[j].y;
                        if (RELU) v = fmaxf(v, 0.f);
                        bout[(size_t)m*ldo + cbase + j*16] = f2bf(v);
                    }
                }
            }
        }
    } else {
        float bj[4];
        #pragma unroll
        for (int j = 0; j < 4; ++j) bj[j] = bias[cbase + j*16];
        #pragma unroll
        for (int i = 0; i < 4; ++i)
            #pragma unroll
            for (int r = 0; r < 4; ++r) {
                int m = rbase + i*16 + r;
                #pragma unroll
                for (int j = 0; j < 4; ++j) {
                    int n = cbase + j*16;
                    float v = acc[i][j][r] + bj[j];
                    if (RESID) v += resid[(size_t)m*CH + n];
                    acc[i][j][r] = v;
                    hout[(size_t)m*CH + n] = v;
                    bout[(size_t)m*CH + n] = f2bf(v);
                }
            }
        if (sbw) {
            #pragma unroll
            for (int i = 0; i < 4; ++i)
                #pragma unroll
                for (int r = 0; r < 4; ++r) {
                    float s = 0.f, q = 0.f;
                    #pragma unroll
                    for (int j = 0; j < 4; ++j) {
                        float v = acc[i][j][r];
                        s += v; q += v*v;
                    }
                    #pragma unroll
                    for (int off = 1; off < 16; off <<= 1) {
                        s += __shfl_xor(s, off);
                        q += __shfl_xor(q, off);
                    }
                    if (l15 == 0) {
                        int m = rbase + i*16 + r;
                        atomicAdd(&sbw[m].x, s);
                        atomicAdd(&sbw[m].y, q);
                    }
                }
        }
    }
}

// ---------------- MFMA attention: Q/K from qkvbf (rope fused), V from transposed vtbuf ----------------
__global__ __launch_bounds__(512) void attn_kernel(
        const ushort* __restrict__ qkv, const ushort* __restrict__ vtbuf,
        const float* __restrict__ mask,
        const float2* __restrict__ tbl, ushort* __restrict__ obuf) {
    __shared__ __align__(16) ushort Kf[8*3*64*8];   // 24 KB
    __shared__ __align__(16) ushort Vf[2*16*64*8];  // 32 KB
    __shared__ float Ms[SEQ];

    const int bid = blockIdx.x;
    const int b   = bid >> 3;
    const int hh  = bid & 7;
    const int tid = threadIdx.x;
    const int lane = tid & 63;
    const int hi   = (lane >> 5);
    const int q5   = lane & 31;
    const ushort* base = qkv + (size_t)b*SEQ*C3;

    // ---- stage K as QK A-fragments, rope fused ----
    {
        int t   = tid >> 6;
        int row = t*32 + q5;
        const ushort* kp = base + (size_t)row*C3 + CH + hh*HD;
        #pragma unroll
        for (int s = 0; s < 3; ++s) {
            union { ushort us[8]; bf16x8 v; } raw;
            raw.v = *(const bf16x8*)(kp + s*16 + hi*8);
            union { uint w[4]; bf16x8 v; } u;
            #pragma unroll
            for (int p = 0; p < 4; ++p) {
                float2 cs = tbl[row*24 + s*8 + hi*4 + p];
                float xu = bfu2f(raw.us[2*p]), xe = bfu2f(raw.us[2*p+1]);
                u.w[p] = pk2(xu*cs.x - xe*cs.y, xu*cs.y + xe*cs.x);
            }
            *(bf16x8*)&Kf[((t*3 + s)*64 + lane)*8] = u.v;
        }
    }
    // ---- stage V^T fragments from vtbuf (16B contiguous loads) ----
    {
        const ushort* vt = vtbuf + (size_t)(b*NHEAD + hh)*HD*SEQ;
        #pragma unroll
        for (int p = 0; p < 4; ++p) {
            int dt = p >> 1;
            int sp = (tid >> 6)*2 + (p & 1);
            int dd = dt*32 + q5;
            bf16x8 u = (bf16x8)(short)0;
            if (dd < HD) u = *(const bf16x8*)(vt + (size_t)dd*SEQ + sp*16 + hi*8);
            *(bf16x8*)&Vf[((dt*16 + sp)*64 + lane)*8] = u;
        }
    }
    if (tid < SEQ) Ms[tid] = mask[b*SEQ + tid];

    // ---- per-wave Q B-fragments (rope + scale fused) ----
    const int wv    = tid >> 6;
    const int qrow  = wv*32 + q5;
    bf16x8 qf[3];
    {
        const ushort* qp = base + (size_t)qrow*C3 + hh*HD;
        #pragma unroll
        for (int s = 0; s < 3; ++s) {
            union { ushort us[8]; bf16x8 v; } raw;
            raw.v = *(const bf16x8*)(qp + s*16 + hi*8);
            union { uint w[4]; bf16x8 v; } u;
            #pragma unroll
            for (int p = 0; p < 4; ++p) {
                float2 cs = tbl[qrow*24 + s*8 + hi*4 + p];
                float xu = bfu2f(raw.us[2*p]), xe = bfu2f(raw.us[2*p+1]);
                u.w[p] = pk2((xu*cs.x - xe*cs.y)*ATT_SCALE, (xu*cs.y + xe*cs.x)*ATT_SCALE);
            }
            qf[s] = u.v;
        }
    }
    __syncthreads();

    // ---- S^T = mfma(K, Q) ----
    f32x16 st[8] = {};
    #pragma unroll
    for (int t = 0; t < 8; ++t)
        #pragma unroll
        for (int s = 0; s < 3; ++s) {
            bf16x8 af = *(const bf16x8*)&Kf[((t*3 + s)*64 + lane)*8];
            st[t] = __builtin_amdgcn_mfma_f32_32x32x16_bf16(af, qf[s], st[t], 0, 0, 0);
        }

    // ---- register softmax ----
    float mx = -1e30f;
    #pragma unroll
    for (int t = 0; t < 8; ++t)
        #pragma unroll
        for (int r = 0; r < 16; ++r) {
            int kt = t*32 + (r & 3) + 8*(r >> 2) + 4*hi;
            float s = st[t][r] + Ms[kt];
            st[t][r] = s;
            mx = fmaxf(mx, s);
        }
    mx = fmaxf(mx, __shfl_xor(mx, 32));
    float sum = 0.f;
    #pragma unroll
    for (int t = 0; t < 8; ++t)
        #pragma unroll
        for (int r = 0; r < 16; ++r) {
            float p = __expf(st[t][r] - mx);
            st[t][r] = p;
            sum += p;
        }
    sum += __shfl_xor(sum, 32);

    // ---- PV: O^T += V^T . P^T ----
    f32x16 oacc[2] = {};
    #pragma unroll
    for (int t = 0; t < 8; ++t) {
        uint w[4][2];
        #pragma unroll
        for (int g = 0; g < 4; ++g) {
            w[g][0] = pk2(st[t][g*4+0], st[t][g*4+1]);
            w[g][1] = pk2(st[t][g*4+2], st[t][g*4+3]);
        }
        #pragma unroll
        for (int o = 0; o < 2; ++o) {
            uint x0 = __shfl_xor(hi ? w[2*o][0] : w[2*o+1][0], 32);
            uint x1 = __shfl_xor(hi ? w[2*o][1] : w[2*o+1][1], 32);
            union { uint w[4]; bf16x8 v; } pf;
            if (hi == 0) { pf.w[0] = w[2*o][0]; pf.w[1] = w[2*o][1]; pf.w[2] = x0; pf.w[3] = x1; }
            else         { pf.w[0] = x0; pf.w[1] = x1; pf.w[2] = w[2*o+1][0]; pf.w[3] = w[2*o+1][1]; }
            int sp = t*2 + o;
            #pragma unroll
            for (int dt = 0; dt < 2; ++dt) {
                bf16x8 vf = *(const bf16x8*)&Vf[((dt*16 + sp)*64 + lane)*8];
                oacc[dt] = __builtin_amdgcn_mfma_f32_32x32x16_bf16(vf, pf.v, oacc[dt], 0, 0, 0);
            }
        }
    }

    float inv = 1.f / sum;
    ushort* op = obuf + ((size_t)(b*SEQ + qrow))*CH + hh*HD;
    #pragma unroll
    for (int dt = 0; dt < 2; ++dt)
        #pragma unroll
        for (int rg = 0; rg < 4; ++rg) {
            int d0 = dt*32 + rg*8 + hi*4;
            if (d0 < HD) {
                uint2 val;
                val.x = pk2(oacc[dt][rg*4+0]*inv, oacc[dt][rg*4+1]*inv);
                val.y = pk2(oacc[dt][rg*4+2]*inv, oacc[dt][rg*4+3]*inv);
                *(uint2*)(op + d0) = val;
            }
        }
}

// ---------------- launcher ----------------
extern "C" void kernel_launch(void* const* d_in, const int* in_sizes, int n_in,
                              void* d_out, int out_size, void* d_ws, size_t ws_size,
                              hipStream_t stream) {
    const float* x      = (const float*)d_in[0];
    const float* mask   = (const float*)d_in[1];
    const float* emb_w1 = (const float*)d_in[2];
    const float* emb_b1 = (const float*)d_in[3];
    const float* emb_w2 = (const float*)d_in[4];
    const float* emb_b2 = (const float*)d_in[5];
    const float* qkv_w  = (const float*)d_in[6];
    const float* proj_w = (const float*)d_in[7];
    const float* proj_b = (const float*)d_in[8];
    const float* mlp_w1 = (const float*)d_in[9];
    const float* mlp_b1 = (const float*)d_in[10];
    const float* mlp_w2 = (const float*)d_in[11];
    const float* mlp_b2 = (const float*)d_in[12];
    const float* ln1_s  = (const float*)d_in[13];
    const float* ln1_b  = (const float*)d_in[14];
    const float* ln2_s  = (const float*)d_in[15];
    const float* ln2_b  = (const float*)d_in[16];

    const size_t S1 = (size_t)NTOK*CH;
    float*  h     = (float*)d_ws;               // fp32 [NTOK][CH]
    ushort* hbf   = (ushort*)(h + S1);          // bf16 shadow of h
    ushort* qkvbf = hbf + S1;                   // bf16 [NTOK][C3] (Q,K regions used)
    ushort* ybf   = qkvbf + 3*S1;               // embed1 out
    ushort* t2bf  = ybf  + S1;
    ushort* obf   = t2bf + S1;
    ushort* vtbuf = obf  + S1;                  // bf16 [B*H*HD][SEQ] transposed V
    ushort* wb_emb2 = vtbuf + S1;                    // 147456
    ushort* wb_proj = wb_emb2 + 147456;              // 884736
    ushort* wb_m2   = wb_proj + 884736;              // 884736
    ushort* wqkvp   = wb_m2   + 884736;              // 2654208
    ushort* wm1p    = wqkvp   + 2654208;             // 884736
    float2* uv_qkv  = (float2*)(wm1p + 884736);      // 6912
    float2* uv_m1   = uv_qkv + 6912;                 // 2304
    float2* sb      = uv_m1  + 2304;                 // 12 x NTOK (sum, sumsq)
    float*  tbl     = (float*)(sb + 12*NTOK);

    dim3 gqkv(9, 128);      // N=1152
    dim3 g384(3, 128);      // N=384

    zero_kernel<<<384, 256, 0, stream>>>((float4*)sb);   // 12*NTOK*2 floats
    rope_table_kernel<<<1, 256, 0, stream>>>((float2*)tbl);
    f2bf4_kernel<<<144, 256, 0, stream>>>(emb_w2, wb_emb2);
    f2bf4_kernel<<<864, 256, 0, stream>>>(proj_w, wb_proj);
    f2bf4_kernel<<<864, 256, 0, stream>>>(mlp_w2, wb_m2);
    prep_kernel<<<1728, 256, 0, stream>>>(qkv_w,  ln1_s, ln1_b, nullptr, C3, wqkvp, uv_qkv);
    prep_kernel<<<576,  256, 0, stream>>>(mlp_w1, ln2_s, ln2_b, mlp_b1,  CH, wm1p,  uv_m1);

    embed1_kernel<<<(NTOK*CH)/256, 256, 0, stream>>>(x, emb_w1, emb_b1, ybf);
    // embed2: h = y@W^T + b ; stats -> sb[0]
    gemm_kernel<false,false,false,false><<<g384, 256, 0, stream>>>(ybf, wb_emb2, emb_b2,
            nullptr, nullptr, nullptr, h, hbf, CH, sb, nullptr);

    for (int i = 0; i < DEPTH; ++i) {
        // qkv (LN1 folded): Q,K -> qkvbf ; V -> vtbuf transposed
        gemm_kernel<true,false,false,true><<<gqkv, 256, 0, stream>>>(hbf,
                wqkvp + (size_t)i*C3*CH, nullptr, uv_qkv + i*C3, sb + (size_t)(2*i)*NTOK,
                nullptr, nullptr, qkvbf, C3, nullptr, vtbuf);
        attn_kernel<<<BATCH*NHEAD, 512, 0, stream>>>(qkvbf, vtbuf, mask,
                (const float2*)tbl, obf);
        // proj + resid ; stats -> sb[2i+1]
        gemm_kernel<false,false,true,false><<<g384, 256, 0, stream>>>(obf,
                wb_proj + (size_t)i*CH*CH, proj_b + i*CH, nullptr, nullptr,
                h, h, hbf, CH, sb + (size_t)(2*i+1)*NTOK, nullptr);
        // mlp1 (LN2 folded, relu)
        gemm_kernel<true,true,false,false><<<g384, 256, 0, stream>>>(hbf,
                wm1p + (size_t)i*CH*CH, nullptr, uv_m1 + i*CH, sb + (size_t)(2*i+1)*NTOK,
                nullptr, nullptr, t2bf, CH, nullptr, nullptr);
        // mlp2 + resid ; stats -> sb[2i+2] (skip last)
        gemm_kernel<false,false,true,false><<<g384, 256, 0, stream>>>(t2bf,
                wb_m2 + (size_t)i*CH*CH, mlp_b2 + i*CH, nullptr, nullptr,
                h, h, hbf, CH, (i < DEPTH-1) ? (sb + (size_t)(2*i+2)*NTOK) : nullptr, nullptr);
    }
    hipMemcpyAsync(d_out, h, S1*sizeof(float), hipMemcpyDeviceToDevice, stream);
}

// Round 11
// 851.403 us; speedup vs baseline: 1.0056x; 1.0056x over previous
//
#include <hip/hip_runtime.h>
#include <hip/hip_bf16.h>
#include <math.h>

#define BATCH 64
#define SEQ   256
#define CH    384
#define NHEAD 8
#define HD    48
#define DEPTH 6
#define NTOK  (BATCH*SEQ)   // 16384
#define C3    (3*CH)        // 1152
#define LN_EPS 1e-5f
#define ATT_SCALE 0.14433756729740643f  // 48^-0.5

typedef __attribute__((ext_vector_type(8)))  short bf16x8;
typedef __attribute__((ext_vector_type(4)))  float f32x4;
typedef __attribute__((ext_vector_type(16))) float f32x16;

__device__ __forceinline__ ushort f2bf(float f) {
    __hip_bfloat16 h = __float2bfloat16(f);
    return *(ushort*)&h;
}
__device__ __forceinline__ float bfu2f(ushort u) {
    uint t = ((uint)u) << 16;
    union { uint u; float f; } c; c.u = t; return c.f;
}
__device__ __forceinline__ uint pk2(float a, float b) {
    return (uint)f2bf(a) | ((uint)f2bf(b) << 16);
}

#define AS1(p) ((const __attribute__((address_space(1))) void*)(p))
#define AS3(p) ((__attribute__((address_space(3))) void*)(uintptr_t)(p))
#define WAITVMC(N) asm volatile("s_waitcnt vmcnt(" #N ")" ::: "memory")
#define TAILSYNC() do { \
    asm volatile("s_waitcnt lgkmcnt(0)" ::: "memory"); \
    __builtin_amdgcn_sched_barrier(0); \
    __builtin_amdgcn_s_barrier(); } while (0)

// ---------------- zero stat accumulators ----------------
__global__ void zero_kernel(float4* __restrict__ p) {
    p[blockIdx.x*256 + threadIdx.x] = float4{0.f,0.f,0.f,0.f};
}

// ---------------- fp32 -> bf16 bulk convert ----------------
__global__ void f2bf4_kernel(const float* __restrict__ in, ushort* __restrict__ out) {
    int i = (blockIdx.x*256 + threadIdx.x)*4;
    float4 v = *(const float4*)(in + i);
    ushort4 o;
    o.x = f2bf(v.x); o.y = f2bf(v.y); o.z = f2bf(v.z); o.w = f2bf(v.w);
    *(ushort4*)(out + i) = o;
}

// ---------------- rope cos/sin table ----------------
__global__ void rope_table_kernel(float2* __restrict__ tbl) {
    int pos = threadIdx.x;
    for (int j = 0; j < 24; ++j) {
        float freq = exp2f(-(float)j * (13.287712379549449f / 24.0f));
        float ang = (float)pos * freq;
        float s, c;
        sincosf(ang, &s, &c);
        tbl[pos*24 + j] = make_float2(c, s);
    }
}

// ---------------- embed stage 1 -> bf16 ----------------
__global__ void embed1_kernel(const float* __restrict__ x, const float* __restrict__ w1,
                              const float* __restrict__ b1, ushort* __restrict__ out) {
    int idx = blockIdx.x*256 + threadIdx.x;
    int m = idx / CH, c = idx - m*CH;
    float v = x[m*2]*w1[c*2] + x[m*2+1]*w1[c*2+1] + b1[c];
    out[idx] = f2bf(fmaxf(v, 0.f));
}

// ---------------- LN-affine weight prep: W' = gam .* W (bf16), uv = {u, v(+bias)} ----------------
__global__ __launch_bounds__(256) void prep_kernel(
        const float* __restrict__ Wsrc, const float* __restrict__ gam,
        const float* __restrict__ bet, const float* __restrict__ bias,
        int npl, ushort* __restrict__ Wdst, float2* __restrict__ uvout) {
    int rr   = blockIdx.x*4 + (threadIdx.x >> 6);
    int lane = threadIdx.x & 63;
    int layer = rr / npl;
    const float* wp = Wsrc + (size_t)rr*CH;
    const float* gp = gam + layer*CH;
    const float* bp = bet + layer*CH;
    float u = 0.f, vv = 0.f;
    if (lane < 48) {
        int c0 = lane*8;
        float w8[8];
        *(float4*)&w8[0] = *(const float4*)(wp + c0);
        *(float4*)&w8[4] = *(const float4*)(wp + c0 + 4);
        union { ushort us[8]; bf16x8 v; } o;
        #pragma unroll
        for (int j = 0; j < 8; ++j) {
            float wg = w8[j] * gp[c0+j];
            u  += wg;
            vv += bp[c0+j] * w8[j];
            o.us[j] = f2bf(wg);
        }
        *(bf16x8*)(Wdst + (size_t)rr*CH + c0) = o.v;
    }
    #pragma unroll
    for (int o = 1; o < 64; o <<= 1) { u += __shfl_xor(u, o); vv += __shfl_xor(vv, o); }
    if (lane == 0) {
        if (bias) vv += bias[rr];
        uvout[rr] = make_float2(u, vv);
    }
}

// ---------------- uniform bf16 MFMA NT-GEMM: BM=128,BN=128,BK=64, ring-2, T2-swizzled, T1 XCD ----
// LNAFF: out = inv_m*(S - mu_m*u_n) + v_n; QKV: Q/K get rope (Q scaled), V -> vtbuf transposed
// else : out = S + bias [+resid] -> h fp32 + hbf bf16; row (sum,sumsq) atomics into sbw
template<bool LNAFF, bool RELU, bool RESID, bool QKV>
__global__ __launch_bounds__(256) void gemm_kernel(
        const ushort* __restrict__ A,      // [M][CH] bf16
        const ushort* __restrict__ W,      // [N][CH] bf16 (W' for LNAFF)
        const float*  __restrict__ bias,   // [N] (non-LNAFF)
        const float2* __restrict__ uv,     // [N] (LNAFF)
        const float2* __restrict__ sbr,    // [M] row sums in (LNAFF)
        const float*  __restrict__ resid,  // [M][CH] fp32 (RESID)
        float*  __restrict__ hout,         // fp32 out (non-LNAFF)
        ushort* __restrict__ bout,         // bf16 out
        int ldo, int nx,
        float2* __restrict__ sbw,          // [M] row sums out (non-LNAFF, may be null)
        ushort* __restrict__ vtbuf,        // [B*H*64][SEQ] transposed V (QKV)
        const float2* __restrict__ tbl) {  // rope table (QKV)
    __shared__ __align__(16) ushort As[2][8192];
    __shared__ __align__(16) ushort Bs[2][8192];
    const int tid  = threadIdx.x;
    const int lane = tid & 63;
    const int w    = tid >> 6;
    const int l15  = lane & 15;
    const int g    = lane >> 4;
    const int wr   = (w >> 1) * 64;
    const int wc   = (w & 1) * 64;
    // T1: XCD-chunked bijective swizzle (gridDim.x % 8 == 0)
    const int lin  = blockIdx.x;
    const int swz  = (lin & 7)*((int)gridDim.x >> 3) + (lin >> 3);
    const int m0   = (swz / nx) * 128;
    const int n0   = (swz % nx) * 128;

    const int srow = lane >> 3;
    const int scol = ((lane & 7) ^ srow) * 8;
    auto stage = [&](int pb, int t) {
        int k0 = t*64;
        #pragma unroll
        for (int c = 0; c < 8; ++c) {
            int chunk = w + c*4;
            if (chunk < 16) {
                const ushort* gp = A + (size_t)(m0 + chunk*8 + srow)*CH + k0 + scol;
                __builtin_amdgcn_global_load_lds(AS1(gp), AS3(&As[pb][chunk*512]), 16, 0, 0);
            } else {
                const ushort* gp = W + (size_t)(n0 + (chunk-16)*8 + srow)*CH + k0 + scol;
                __builtin_amdgcn_global_load_lds(AS1(gp), AS3(&Bs[pb][(chunk-16)*512]), 16, 0, 0);
            }
        }
    };

    f32x4 acc[4][4] = {};
    const int xm = (l15 & 7) << 4;

    stage(0, 0);
    for (int t = 0; t < 6; ++t) {
        if (t + 1 < 6) stage((t+1)&1, t+1);
        if (t < 5) { WAITVMC(8); } else { WAITVMC(0); }
        __builtin_amdgcn_s_barrier();
        const int pb = t & 1;
        #pragma unroll
        for (int kk = 0; kk < 2; ++kk) {
            bf16x8 a[4], b[4];
            #pragma unroll
            for (int i = 0; i < 4; ++i)
                a[i] = *(const bf16x8*)((const char*)As[pb]
                        + (wr + i*16 + l15)*128 + ((kk*64 + 16*g) ^ xm));
            #pragma unroll
            for (int j = 0; j < 4; ++j)
                b[j] = *(const bf16x8*)((const char*)Bs[pb]
                        + (wc + j*16 + l15)*128 + ((kk*64 + 16*g) ^ xm));
            #pragma unroll
            for (int i = 0; i < 4; ++i)
                #pragma unroll
                for (int j = 0; j < 4; ++j)
                    acc[i][j] = __builtin_amdgcn_mfma_f32_16x16x32_bf16(a[i], b[j], acc[i][j], 0, 0, 0);
        }
        TAILSYNC();
    }

    const int cbase = n0 + wc + l15;
    const int rbase = m0 + wr + g*4;
    if (LNAFF) {
        float2 uvv[4];
        #pragma unroll
        for (int j = 0; j < 4; ++j) uvv[j] = uv[cbase + j*16];
        const int region = QKV ? (n0 / 384) : 0;    // 0=Q 1=K 2=V (uniform per block)
        int hj[4], dj[4], jp[4];
        if (QKV) {
            #pragma unroll
            for (int j = 0; j < 4; ++j) {
                int nn = cbase + j*16 - region*384;
                if (region == 2) { hj[j] = nn / HD; dj[j] = nn - hj[j]*HD; }
                else             { jp[j] = (nn % HD) >> 1; }
            }
        }
        #pragma unroll
        for (int i = 0; i < 4; ++i) {
            float muv[4], invv[4];
            #pragma unroll
            for (int r = 0; r < 4; ++r) {
                float2 s2 = sbr[rbase + i*16 + r];
                float mu = s2.x * (1.0f/CH);
                float var = s2.y * (1.0f/CH) - mu*mu;
                muv[r] = mu; invv[r] = rsqrtf(var + LN_EPS);
            }
            if (QKV && region == 2) {
                int bb   = rbase >> 8;
                int seq0 = (rbase + i*16) & 255;
                #pragma unroll
                for (int j = 0; j < 4; ++j) {
                    float vr[4];
                    #pragma unroll
                    for (int r = 0; r < 4; ++r)
                        vr[r] = invv[r]*(acc[i][j][r] - muv[r]*uvv[j].x) + uvv[j].y;
                    uint2 val;
                    val.x = pk2(vr[0], vr[1]);
                    val.y = pk2(vr[2], vr[3]);
                    *(uint2*)(vtbuf + (((size_t)bb*NHEAD + hj[j])*64 + dj[j])*SEQ + seq0) = val;
                }
            } else {
                #pragma unroll
                for (int r = 0; r < 4; ++r) {
                    int m = rbase + i*16 + r;
                    int pos = m & 255;
                    #pragma unroll
                    for (int j = 0; j < 4; ++j) {
                        float v = invv[r]*(acc[i][j][r] - muv[r]*uvv[j].x) + uvv[j].y;
                        if (QKV) {   // Q/K rope: pair value lives in neighbor lane
                            float vx = __shfl_xor(v, 1);
                            float2 cs = tbl[pos*24 + jp[j]];
                            v = (l15 & 1) ? (vx*cs.y + v*cs.x) : (v*cs.x - vx*cs.y);
                            if (region == 0) v *= ATT_SCALE;
                        }
                        if (RELU) v = fmaxf(v, 0.f);
                        bout[(size_t)m*ldo + cbase + j*16] = f2bf(v);
                    }
                }
            }
        }
    } else {
        float bj[4];
        #pragma unroll
        for (int j = 0; j < 4; ++j) bj[j] = bias[cbase + j*16];
        #pragma unroll
        for (int i = 0; i < 4; ++i)
            #pragma unroll
            for (int r = 0; r < 4; ++r) {
                int m = rbase + i*16 + r;
                #pragma unroll
                for (int j = 0; j < 4; ++j) {
                    int n = cbase + j*16;
                    float v = acc[i][j][r] + bj[j];
                    if (RESID) v += resid[(size_t)m*CH + n];
                    acc[i][j][r] = v;
                    hout[(size_t)m*CH + n] = v;
                    bout[(size_t)m*CH + n] = f2bf(v);
                }
            }
        if (sbw) {
            #pragma unroll
            for (int i = 0; i < 4; ++i)
                #pragma unroll
                for (int r = 0; r < 4; ++r) {
                    float s = 0.f, q = 0.f;
                    #pragma unroll
                    for (int j = 0; j < 4; ++j) {
                        float v = acc[i][j][r];
                        s += v; q += v*v;
                    }
                    #pragma unroll
                    for (int off = 1; off < 16; off <<= 1) {
                        s += __shfl_xor(s, off);
                        q += __shfl_xor(q, off);
                    }
                    if (l15 == 0) {
                        int m = rbase + i*16 + r;
                        atomicAdd(&sbw[m].x, s);
                        atomicAdd(&sbw[m].y, q);
                    }
                }
        }
    }
}

// ---------------- MFMA attention: rope'd Q/K in qkvbf, V^T in vtbuf; pure gload_lds staging ----
__global__ __launch_bounds__(512) void attn_kernel(
        const ushort* __restrict__ qkv, const ushort* __restrict__ vtbuf,
        const float* __restrict__ mask, ushort* __restrict__ obuf) {
    __shared__ __align__(16) ushort Kf[8*3*64*8];   // 24 KB
    __shared__ __align__(16) ushort Vf[2*16*64*8];  // 32 KB
    __shared__ float Ms[SEQ];

    const int bid = blockIdx.x;
    const int b   = bid >> 3;
    const int hh  = bid & 7;
    const int tid = threadIdx.x;
    const int lane = tid & 63;
    const int hi   = (lane >> 5);
    const int q5   = lane & 31;
    const int twv  = tid >> 6;
    const ushort* base = qkv + (size_t)b*SEQ*C3;

    // ---- K fragments via global_load_lds (3 per wave; per-lane src, uniform LDS base) ----
    {
        int row = twv*32 + q5;
        const ushort* kp = base + (size_t)row*C3 + CH + hh*HD + hi*8;
        #pragma unroll
        for (int s = 0; s < 3; ++s)
            __builtin_amdgcn_global_load_lds(AS1(kp + s*16), AS3(&Kf[(twv*3+s)*512]), 16, 0, 0);
    }
    // ---- V^T fragments via global_load_lds (4 per wave; d-rows 48..63 read benign pad) ----
    {
        const ushort* vt = vtbuf + (size_t)(b*NHEAD + hh)*64*SEQ;
        #pragma unroll
        for (int p = 0; p < 4; ++p) {
            int dt = p >> 1;
            int sp = twv*2 + (p & 1);
            int dd = dt*32 + q5;
            const ushort* vp = vt + (size_t)dd*SEQ + sp*16 + hi*8;
            __builtin_amdgcn_global_load_lds(AS1(vp), AS3(&Vf[(dt*16+sp)*512]), 16, 0, 0);
        }
    }
    if (tid < SEQ) Ms[tid] = mask[b*SEQ + tid];

    // ---- Q fragments: direct loads (rope'd + scaled already) ----
    const int qrow = twv*32 + q5;
    bf16x8 qf[3];
    {
        const ushort* qp = base + (size_t)qrow*C3 + hh*HD + hi*8;
        #pragma unroll
        for (int s = 0; s < 3; ++s) qf[s] = *(const bf16x8*)(qp + s*16);
    }
    __syncthreads();

    // ---- S^T = mfma(K, Q) ----
    f32x16 st[8] = {};
    #pragma unroll
    for (int t = 0; t < 8; ++t)
        #pragma unroll
        for (int s = 0; s < 3; ++s) {
            bf16x8 af = *(const bf16x8*)&Kf[((t*3 + s)*64 + lane)*8];
            st[t] = __builtin_amdgcn_mfma_f32_32x32x16_bf16(af, qf[s], st[t], 0, 0, 0);
        }

    // ---- register softmax ----
    float mx = -1e30f;
    #pragma unroll
    for (int t = 0; t < 8; ++t)
        #pragma unroll
        for (int r = 0; r < 16; ++r) {
            int kt = t*32 + (r & 3) + 8*(r >> 2) + 4*hi;
            float s = st[t][r] + Ms[kt];
            st[t][r] = s;
            mx = fmaxf(mx, s);
        }
    mx = fmaxf(mx, __shfl_xor(mx, 32));
    float sum = 0.f;
    #pragma unroll
    for (int t = 0; t < 8; ++t)
        #pragma unroll
        for (int r = 0; r < 16; ++r) {
            float p = __expf(st[t][r] - mx);
            st[t][r] = p;
            sum += p;
        }
    sum += __shfl_xor(sum, 32);

    // ---- PV: O^T += V^T . P^T ----
    f32x16 oacc[2] = {};
    #pragma unroll
    for (int t = 0; t < 8; ++t) {
        uint w[4][2];
        #pragma unroll
        for (int g = 0; g < 4; ++g) {
            w[g][0] = pk2(st[t][g*4+0], st[t][g*4+1]);
            w[g][1] = pk2(st[t][g*4+2], st[t][g*4+3]);
        }
        #pragma unroll
        for (int o = 0; o < 2; ++o) {
            uint x0 = __shfl_xor(hi ? w[2*o][0] : w[2*o+1][0], 32);
            uint x1 = __shfl_xor(hi ? w[2*o][1] : w[2*o+1][1], 32);
            union { uint w[4]; bf16x8 v; } pf;
            if (hi == 0) { pf.w[0] = w[2*o][0]; pf.w[1] = w[2*o][1]; pf.w[2] = x0; pf.w[3] = x1; }
            else         { pf.w[0] = x0; pf.w[1] = x1; pf.w[2] = w[2*o+1][0]; pf.w[3] = w[2*o+1][1]; }
            int sp = t*2 + o;
            #pragma unroll
            for (int dt = 0; dt < 2; ++dt) {
                bf16x8 vf = *(const bf16x8*)&Vf[((dt*16 + sp)*64 + lane)*8];
                oacc[dt] = __builtin_amdgcn_mfma_f32_32x32x16_bf16(vf, pf.v, oacc[dt], 0, 0, 0);
            }
        }
    }

    float inv = 1.f / sum;
    ushort* op = obuf + ((size_t)(b*SEQ + qrow))*CH + hh*HD;
    #pragma unroll
    for (int dt = 0; dt < 2; ++dt)
        #pragma unroll
        for (int rg = 0; rg < 4; ++rg) {
            int d0 = dt*32 + rg*8 + hi*4;
            if (d0 < HD) {
                uint2 val;
                val.x = pk2(oacc[dt][rg*4+0]*inv, oacc[dt][rg*4+1]*inv);
                val.y = pk2(oacc[dt][rg*4+2]*inv, oacc[dt][rg*4+3]*inv);
                *(uint2*)(op + d0) = val;
            }
        }
}

// ---------------- launcher ----------------
extern "C" void kernel_launch(void* const* d_in, const int* in_sizes, int n_in,
                              void* d_out, int out_size, void* d_ws, size_t ws_size,
                              hipStream_t stream) {
    const float* x      = (const float*)d_in[0];
    const float* mask   = (const float*)d_in[1];
    const float* emb_w1 = (const float*)d_in[2];
    const float* emb_b1 = (const float*)d_in[3];
    const float* emb_w2 = (const float*)d_in[4];
    const float* emb_b2 = (const float*)d_in[5];
    const float* qkv_w  = (const float*)d_in[6];
    const float* proj_w = (const float*)d_in[7];
    const float* proj_b = (const float*)d_in[8];
    const float* mlp_w1 = (const float*)d_in[9];
    const float* mlp_b1 = (const float*)d_in[10];
    const float* mlp_w2 = (const float*)d_in[11];
    const float* mlp_b2 = (const float*)d_in[12];
    const float* ln1_s  = (const float*)d_in[13];
    const float* ln1_b  = (const float*)d_in[14];
    const float* ln2_s  = (const float*)d_in[15];
    const float* ln2_b  = (const float*)d_in[16];

    const size_t S1 = (size_t)NTOK*CH;
    float*  h     = (float*)d_ws;               // fp32 [NTOK][CH]
    ushort* hbf   = (ushort*)(h + S1);          // bf16 shadow of h
    ushort* qkvbf = hbf + S1;                   // bf16 [NTOK][C3] (rope'd Q/K)
    ushort* ybf   = qkvbf + 3*S1;               // embed1 out
    ushort* t2bf  = ybf  + S1;
    ushort* obf   = t2bf + S1;
    ushort* vtbuf = obf  + S1;                  // bf16 [B*H*64][SEQ] transposed V (d padded)
    ushort* wb_emb2 = vtbuf + (size_t)BATCH*NHEAD*64*SEQ;
    ushort* wb_proj = wb_emb2 + 147456;
    ushort* wb_m2   = wb_proj + 884736;
    ushort* wqkvp   = wb_m2   + 884736;
    ushort* wm1p    = wqkvp   + 2654208;
    float2* uv_qkv  = (float2*)(wm1p + 884736);
    float2* uv_m1   = uv_qkv + 6912;
    float2* sb      = uv_m1  + 2304;            // 12 x NTOK (sum, sumsq)
    float*  tbl     = (float*)(sb + 12*NTOK);
    const float2* tblc = (const float2*)tbl;

    zero_kernel<<<384, 256, 0, stream>>>((float4*)sb);
    rope_table_kernel<<<1, 256, 0, stream>>>((float2*)tbl);
    f2bf4_kernel<<<144, 256, 0, stream>>>(emb_w2, wb_emb2);
    f2bf4_kernel<<<864, 256, 0, stream>>>(proj_w, wb_proj);
    f2bf4_kernel<<<864, 256, 0, stream>>>(mlp_w2, wb_m2);
    prep_kernel<<<1728, 256, 0, stream>>>(qkv_w,  ln1_s, ln1_b, nullptr, C3, wqkvp, uv_qkv);
    prep_kernel<<<576,  256, 0, stream>>>(mlp_w1, ln2_s, ln2_b, mlp_b1,  CH, wm1p,  uv_m1);

    embed1_kernel<<<(NTOK*CH)/256, 256, 0, stream>>>(x, emb_w1, emb_b1, ybf);
    gemm_kernel<false,false,false,false><<<384, 256, 0, stream>>>(ybf, wb_emb2, emb_b2,
            nullptr, nullptr, nullptr, h, hbf, CH, 3, sb, nullptr, nullptr);

    for (int i = 0; i < DEPTH; ++i) {
        // qkv (LN1 folded): Q/K rope'd -> qkvbf ; V -> vtbuf transposed
        gemm_kernel<true,false,false,true><<<1152, 256, 0, stream>>>(hbf,
                wqkvp + (size_t)i*C3*CH, nullptr, uv_qkv + i*C3, sb + (size_t)(2*i)*NTOK,
                nullptr, nullptr, qkvbf, C3, 9, nullptr, vtbuf, tblc);
        attn_kernel<<<BATCH*NHEAD, 512, 0, stream>>>(qkvbf, vtbuf, mask, obf);
        // proj + resid ; stats -> sb[2i+1]
        gemm_kernel<false,false,true,false><<<384, 256, 0, stream>>>(obf,
                wb_proj + (size_t)i*CH*CH, proj_b + i*CH, nullptr, nullptr,
                h, h, hbf, CH, 3, sb + (size_t)(2*i+1)*NTOK, nullptr, nullptr);
        // mlp1 (LN2 folded, relu)
        gemm_kernel<true,true,false,false><<<384, 256, 0, stream>>>(hbf,
                wm1p + (size_t)i*CH*CH, nullptr, uv_m1 + i*CH, sb + (size_t)(2*i+1)*NTOK,
                nullptr, nullptr, t2bf, CH, 3, nullptr, nullptr, nullptr);
        // mlp2 + resid ; stats -> sb[2i+2] (skip last)
        gemm_kernel<false,false,true,false><<<384, 256, 0, stream>>>(t2bf,
                wb_m2 + (size_t)i*CH*CH, mlp_b2 + i*CH, nullptr, nullptr,
                h, h, hbf, CH, 3, (i < DEPTH-1) ? (sb + (size_t)(2*i+2)*NTOK) : nullptr,
                nullptr, nullptr);
    }
    hipMemcpyAsync(d_out, h, S1*sizeof(float), hipMemcpyDeviceToDevice, stream);
}

// Round 12
// 846.466 us; speedup vs baseline: 1.0114x; 1.0058x over previous
//
#include <hip/hip_runtime.h>
#include <hip/hip_bf16.h>
#include <math.h>

#define BATCH 64
#define SEQ   256
#define CH    384
#define NHEAD 8
#define HD    48
#define DEPTH 6
#define NTOK  (BATCH*SEQ)   // 16384
#define C3    (3*CH)        // 1152
#define LN_EPS 1e-5f
#define ATT_SCALE 0.14433756729740643f  // 48^-0.5

typedef __attribute__((ext_vector_type(8)))  short bf16x8;
typedef __attribute__((ext_vector_type(4)))  float f32x4;
typedef __attribute__((ext_vector_type(16))) float f32x16;

__device__ __forceinline__ ushort f2bf(float f) {
    __hip_bfloat16 h = __float2bfloat16(f);
    return *(ushort*)&h;
}
__device__ __forceinline__ float bfu2f(ushort u) {
    uint t = ((uint)u) << 16;
    union { uint u; float f; } c; c.u = t; return c.f;
}
__device__ __forceinline__ uint pk2(float a, float b) {
    return (uint)f2bf(a) | ((uint)f2bf(b) << 16);
}

#define AS1(p) ((const __attribute__((address_space(1))) void*)(p))
#define AS3(p) ((__attribute__((address_space(3))) void*)(uintptr_t)(p))
#define WAITVMC(N) asm volatile("s_waitcnt vmcnt(" #N ")" ::: "memory")
#define TAILSYNC() do { \
    asm volatile("s_waitcnt lgkmcnt(0)" ::: "memory"); \
    __builtin_amdgcn_sched_barrier(0); \
    __builtin_amdgcn_s_barrier(); } while (0)

// ---------------- init: zero stat accumulators + rope table ----------------
__global__ void init_kernel(float4* __restrict__ sb, float2* __restrict__ tbl) {
    int bid = blockIdx.x;
    if (bid < 384) {
        sb[bid*256 + threadIdx.x] = float4{0.f,0.f,0.f,0.f};
    } else {
        int pos = threadIdx.x;
        for (int j = 0; j < 24; ++j) {
            float freq = exp2f(-(float)j * (13.287712379549449f / 24.0f));
            float ang = (float)pos * freq;
            float s, c;
            sincosf(ang, &s, &c);
            tbl[pos*24 + j] = make_float2(c, s);
        }
    }
}

// ---------------- fp32 -> bf16 bulk convert (3 weight tensors, one launch) ----------------
__global__ void f2bf3_kernel(const float* __restrict__ s0, const float* __restrict__ s1,
                             const float* __restrict__ s2, ushort* __restrict__ dst) {
    int bid = blockIdx.x;
    const float* src;
    int loc;
    if (bid < 144)      { src = s0; loc = bid; }
    else if (bid < 1008){ src = s1; loc = bid - 144; }
    else                { src = s2; loc = bid - 1008; }
    int li = loc*1024 + threadIdx.x*4;
    float4 v = *(const float4*)(src + li);
    ushort4 o;
    o.x = f2bf(v.x); o.y = f2bf(v.y); o.z = f2bf(v.z); o.w = f2bf(v.w);
    *(ushort4*)(dst + (size_t)bid*1024 + threadIdx.x*4) = o;
}

// ---------------- embed stage 1 -> bf16 ----------------
__global__ void embed1_kernel(const float* __restrict__ x, const float* __restrict__ w1,
                              const float* __restrict__ b1, ushort* __restrict__ out) {
    int idx = blockIdx.x*256 + threadIdx.x;
    int m = idx / CH, c = idx - m*CH;
    float v = x[m*2]*w1[c*2] + x[m*2+1]*w1[c*2+1] + b1[c];
    out[idx] = f2bf(fmaxf(v, 0.f));
}

// ---------------- LN-affine weight prep: W' = gam .* W (bf16), uv = {u, v(+bias)} ----------------
__global__ __launch_bounds__(256) void prep_kernel(
        const float* __restrict__ Wsrc, const float* __restrict__ gam,
        const float* __restrict__ bet, const float* __restrict__ bias,
        int npl, ushort* __restrict__ Wdst, float2* __restrict__ uvout) {
    int rr   = blockIdx.x*4 + (threadIdx.x >> 6);
    int lane = threadIdx.x & 63;
    int layer = rr / npl;
    const float* wp = Wsrc + (size_t)rr*CH;
    const float* gp = gam + layer*CH;
    const float* bp = bet + layer*CH;
    float u = 0.f, vv = 0.f;
    if (lane < 48) {
        int c0 = lane*8;
        float w8[8];
        *(float4*)&w8[0] = *(const float4*)(wp + c0);
        *(float4*)&w8[4] = *(const float4*)(wp + c0 + 4);
        union { ushort us[8]; bf16x8 v; } o;
        #pragma unroll
        for (int j = 0; j < 8; ++j) {
            float wg = w8[j] * gp[c0+j];
            u  += wg;
            vv += bp[c0+j] * w8[j];
            o.us[j] = f2bf(wg);
        }
        *(bf16x8*)(Wdst + (size_t)rr*CH + c0) = o.v;
    }
    #pragma unroll
    for (int o = 1; o < 64; o <<= 1) { u += __shfl_xor(u, o); vv += __shfl_xor(vv, o); }
    if (lane == 0) {
        if (bias) vv += bias[rr];
        uvout[rr] = make_float2(u, vv);
    }
}

// ---------------- bf16 MFMA NT-GEMM: BM=64,BN=128,BK=64, ring-2, T2-swizzled, T1 XCD ----------------
// 3 blocks/CU (48KB LDS), zero-tail grids (768 / 2304).
template<bool LNAFF, bool RELU, bool RESID, bool QKV>
__global__ __launch_bounds__(256) void gemm_kernel(
        const ushort* __restrict__ A,      // [M][CH] bf16
        const ushort* __restrict__ W,      // [N][CH] bf16 (W' for LNAFF)
        const float*  __restrict__ bias,   // [N] (non-LNAFF)
        const float2* __restrict__ uv,     // [N] (LNAFF)
        const float2* __restrict__ sbr,    // [M] row sums in (LNAFF)
        const float*  __restrict__ resid,  // [M][CH] fp32 (RESID)
        float*  __restrict__ hout,         // fp32 out (non-LNAFF)
        ushort* __restrict__ bout,         // bf16 out
        int ldo, int nx,
        float2* __restrict__ sbw,          // [M] row sums out (non-LNAFF, may be null)
        ushort* __restrict__ vtbuf,        // [B*H*64][SEQ] transposed V (QKV)
        const float2* __restrict__ tbl) {  // rope table (QKV)
    __shared__ __align__(16) ushort As[2][4096];    // 8KB x2
    __shared__ __align__(16) ushort Bs[2][8192];    // 16KB x2
    const int tid  = threadIdx.x;
    const int lane = tid & 63;
    const int w    = tid >> 6;
    const int l15  = lane & 15;
    const int g    = lane >> 4;
    const int wr   = (w >> 1) * 32;
    const int wc   = (w & 1) * 64;
    // T1: XCD-chunked bijective swizzle (gridDim.x % 8 == 0)
    const int lin  = blockIdx.x;
    const int swz  = (lin & 7)*((int)gridDim.x >> 3) + (lin >> 3);
    const int m0   = (swz / nx) * 64;
    const int n0   = (swz % nx) * 128;

    const int srow = lane >> 3;
    const int scol = ((lane & 7) ^ srow) * 8;
    auto stage = [&](int pb, int t) {
        int k0 = t*64;
        #pragma unroll
        for (int c = 0; c < 6; ++c) {
            int chunk = w + c*4;   // 24 chunks: 8 A + 16 B
            if (chunk < 8) {
                const ushort* gp = A + (size_t)(m0 + chunk*8 + srow)*CH + k0 + scol;
                __builtin_amdgcn_global_load_lds(AS1(gp), AS3(&As[pb][chunk*512]), 16, 0, 0);
            } else {
                const ushort* gp = W + (size_t)(n0 + (chunk-8)*8 + srow)*CH + k0 + scol;
                __builtin_amdgcn_global_load_lds(AS1(gp), AS3(&Bs[pb][(chunk-8)*512]), 16, 0, 0);
            }
        }
    };

    f32x4 acc[2][4] = {};
    const int xm = (l15 & 7) << 4;

    stage(0, 0);
    for (int t = 0; t < 6; ++t) {
        if (t + 1 < 6) stage((t+1)&1, t+1);
        if (t < 5) { WAITVMC(6); } else { WAITVMC(0); }
        __builtin_amdgcn_s_barrier();
        const int pb = t & 1;
        #pragma unroll
        for (int kk = 0; kk < 2; ++kk) {
            bf16x8 a[2], b[4];
            #pragma unroll
            for (int i = 0; i < 2; ++i)
                a[i] = *(const bf16x8*)((const char*)As[pb]
                        + (wr + i*16 + l15)*128 + ((kk*64 + 16*g) ^ xm));
            #pragma unroll
            for (int j = 0; j < 4; ++j)
                b[j] = *(const bf16x8*)((const char*)Bs[pb]
                        + (wc + j*16 + l15)*128 + ((kk*64 + 16*g) ^ xm));
            #pragma unroll
            for (int i = 0; i < 2; ++i)
                #pragma unroll
                for (int j = 0; j < 4; ++j)
                    acc[i][j] = __builtin_amdgcn_mfma_f32_16x16x32_bf16(a[i], b[j], acc[i][j], 0, 0, 0);
        }
        TAILSYNC();
    }

    const int cbase = n0 + wc + l15;
    const int rbase = m0 + wr + g*4;
    if (LNAFF) {
        float2 uvv[4];
        #pragma unroll
        for (int j = 0; j < 4; ++j) uvv[j] = uv[cbase + j*16];
        const int region = QKV ? (n0 / 384) : 0;    // 0=Q 1=K 2=V (uniform per block)
        int hj[4], dj[4], jp[4];
        if (QKV) {
            #pragma unroll
            for (int j = 0; j < 4; ++j) {
                int nn = cbase + j*16 - region*384;
                if (region == 2) { hj[j] = nn / HD; dj[j] = nn - hj[j]*HD; }
                else             { jp[j] = (nn % HD) >> 1; }
            }
        }
        #pragma unroll
        for (int i = 0; i < 2; ++i) {
            float muv[4], invv[4];
            #pragma unroll
            for (int r = 0; r < 4; ++r) {
                float2 s2 = sbr[rbase + i*16 + r];
                float mu = s2.x * (1.0f/CH);
                float var = s2.y * (1.0f/CH) - mu*mu;
                muv[r] = mu; invv[r] = rsqrtf(var + LN_EPS);
            }
            if (QKV && region == 2) {
                int bb   = rbase >> 8;
                int seq0 = (rbase + i*16) & 255;
                #pragma unroll
                for (int j = 0; j < 4; ++j) {
                    float vr[4];
                    #pragma unroll
                    for (int r = 0; r < 4; ++r)
                        vr[r] = invv[r]*(acc[i][j][r] - muv[r]*uvv[j].x) + uvv[j].y;
                    uint2 val;
                    val.x = pk2(vr[0], vr[1]);
                    val.y = pk2(vr[2], vr[3]);
                    *(uint2*)(vtbuf + (((size_t)bb*NHEAD + hj[j])*64 + dj[j])*SEQ + seq0) = val;
                }
            } else {
                #pragma unroll
                for (int r = 0; r < 4; ++r) {
                    int m = rbase + i*16 + r;
                    int pos = m & 255;
                    #pragma unroll
                    for (int j = 0; j < 4; ++j) {
                        float v = invv[r]*(acc[i][j][r] - muv[r]*uvv[j].x) + uvv[j].y;
                        if (QKV) {   // Q/K rope: pair value lives in neighbor lane
                            float vx = __shfl_xor(v, 1);
                            float2 cs = tbl[pos*24 + jp[j]];
                            v = (l15 & 1) ? (vx*cs.y + v*cs.x) : (v*cs.x - vx*cs.y);
                            if (region == 0) v *= ATT_SCALE;
                        }
                        if (RELU) v = fmaxf(v, 0.f);
                        bout[(size_t)m*ldo + cbase + j*16] = f2bf(v);
                    }
                }
            }
        }
    } else {
        float bj[4];
        #pragma unroll
        for (int j = 0; j < 4; ++j) bj[j] = bias[cbase + j*16];
        #pragma unroll
        for (int i = 0; i < 2; ++i)
            #pragma unroll
            for (int r = 0; r < 4; ++r) {
                int m = rbase + i*16 + r;
                #pragma unroll
                for (int j = 0; j < 4; ++j) {
                    int n = cbase + j*16;
                    float v = acc[i][j][r] + bj[j];
                    if (RESID) v += resid[(size_t)m*CH + n];
                    acc[i][j][r] = v;
                    hout[(size_t)m*CH + n] = v;
                    bout[(size_t)m*CH + n] = f2bf(v);
                }
            }
        if (sbw) {
            #pragma unroll
            for (int i = 0; i < 2; ++i)
                #pragma unroll
                for (int r = 0; r < 4; ++r) {
                    float s = 0.f, q = 0.f;
                    #pragma unroll
                    for (int j = 0; j < 4; ++j) {
                        float v = acc[i][j][r];
                        s += v; q += v*v;
                    }
                    #pragma unroll
                    for (int off = 1; off < 16; off <<= 1) {
                        s += __shfl_xor(s, off);
                        q += __shfl_xor(q, off);
                    }
                    if (l15 == 0) {
                        int m = rbase + i*16 + r;
                        atomicAdd(&sbw[m].x, s);
                        atomicAdd(&sbw[m].y, q);
                    }
                }
        }
    }
}

// ---------------- MFMA attention: rope'd Q/K in qkvbf, V^T in vtbuf; pure gload_lds staging ----
__global__ __launch_bounds__(512) void attn_kernel(
        const ushort* __restrict__ qkv, const ushort* __restrict__ vtbuf,
        const float* __restrict__ mask, ushort* __restrict__ obuf) {
    __shared__ __align__(16) ushort Kf[8*3*64*8];   // 24 KB
    __shared__ __align__(16) ushort Vf[2*16*64*8];  // 32 KB
    __shared__ float Ms[SEQ];

    const int bid = blockIdx.x;
    const int b   = bid >> 3;
    const int hh  = bid & 7;
    const int tid = threadIdx.x;
    const int lane = tid & 63;
    const int hi   = (lane >> 5);
    const int q5   = lane & 31;
    const int twv  = tid >> 6;
    const ushort* base = qkv + (size_t)b*SEQ*C3;

    // ---- K fragments via global_load_lds ----
    {
        int row = twv*32 + q5;
        const ushort* kp = base + (size_t)row*C3 + CH + hh*HD + hi*8;
        #pragma unroll
        for (int s = 0; s < 3; ++s)
            __builtin_amdgcn_global_load_lds(AS1(kp + s*16), AS3(&Kf[(twv*3+s)*512]), 16, 0, 0);
    }
    // ---- V^T fragments via global_load_lds (d-rows 48..63 read benign pad) ----
    {
        const ushort* vt = vtbuf + (size_t)(b*NHEAD + hh)*64*SEQ;
        #pragma unroll
        for (int p = 0; p < 4; ++p) {
            int dt = p >> 1;
            int sp = twv*2 + (p & 1);
            int dd = dt*32 + q5;
            const ushort* vp = vt + (size_t)dd*SEQ + sp*16 + hi*8;
            __builtin_amdgcn_global_load_lds(AS1(vp), AS3(&Vf[(dt*16+sp)*512]), 16, 0, 0);
        }
    }
    if (tid < SEQ) Ms[tid] = mask[b*SEQ + tid];

    // ---- Q fragments: direct loads (rope'd + scaled already) ----
    const int qrow = twv*32 + q5;
    bf16x8 qf[3];
    {
        const ushort* qp = base + (size_t)qrow*C3 + hh*HD + hi*8;
        #pragma unroll
        for (int s = 0; s < 3; ++s) qf[s] = *(const bf16x8*)(qp + s*16);
    }
    __syncthreads();

    // ---- S^T = mfma(K, Q) ----
    f32x16 st[8] = {};
    #pragma unroll
    for (int t = 0; t < 8; ++t)
        #pragma unroll
        for (int s = 0; s < 3; ++s) {
            bf16x8 af = *(const bf16x8*)&Kf[((t*3 + s)*64 + lane)*8];
            st[t] = __builtin_amdgcn_mfma_f32_32x32x16_bf16(af, qf[s], st[t], 0, 0, 0);
        }

    // ---- register softmax ----
    float mx = -1e30f;
    #pragma unroll
    for (int t = 0; t < 8; ++t)
        #pragma unroll
        for (int r = 0; r < 16; ++r) {
            int kt = t*32 + (r & 3) + 8*(r >> 2) + 4*hi;
            float s = st[t][r] + Ms[kt];
            st[t][r] = s;
            mx = fmaxf(mx, s);
        }
    mx = fmaxf(mx, __shfl_xor(mx, 32));
    float sum = 0.f;
    #pragma unroll
    for (int t = 0; t < 8; ++t)
        #pragma unroll
        for (int r = 0; r < 16; ++r) {
            float p = __expf(st[t][r] - mx);
            st[t][r] = p;
            sum += p;
        }
    sum += __shfl_xor(sum, 32);

    // ---- PV: O^T += V^T . P^T ----
    f32x16 oacc[2] = {};
    #pragma unroll
    for (int t = 0; t < 8; ++t) {
        uint w[4][2];
        #pragma unroll
        for (int g = 0; g < 4; ++g) {
            w[g][0] = pk2(st[t][g*4+0], st[t][g*4+1]);
            w[g][1] = pk2(st[t][g*4+2], st[t][g*4+3]);
        }
        #pragma unroll
        for (int o = 0; o < 2; ++o) {
            uint x0 = __shfl_xor(hi ? w[2*o][0] : w[2*o+1][0], 32);
            uint x1 = __shfl_xor(hi ? w[2*o][1] : w[2*o+1][1], 32);
            union { uint w[4]; bf16x8 v; } pf;
            if (hi == 0) { pf.w[0] = w[2*o][0]; pf.w[1] = w[2*o][1]; pf.w[2] = x0; pf.w[3] = x1; }
            else         { pf.w[0] = x0; pf.w[1] = x1; pf.w[2] = w[2*o+1][0]; pf.w[3] = w[2*o+1][1]; }
            int sp = t*2 + o;
            #pragma unroll
            for (int dt = 0; dt < 2; ++dt) {
                bf16x8 vf = *(const bf16x8*)&Vf[((dt*16 + sp)*64 + lane)*8];
                oacc[dt] = __builtin_amdgcn_mfma_f32_32x32x16_bf16(vf, pf.v, oacc[dt], 0, 0, 0);
            }
        }
    }

    float inv = 1.f / sum;
    ushort* op = obuf + ((size_t)(b*SEQ + qrow))*CH + hh*HD;
    #pragma unroll
    for (int dt = 0; dt < 2; ++dt)
        #pragma unroll
        for (int rg = 0; rg < 4; ++rg) {
            int d0 = dt*32 + rg*8 + hi*4;
            if (d0 < HD) {
                uint2 val;
                val.x = pk2(oacc[dt][rg*4+0]*inv, oacc[dt][rg*4+1]*inv);
                val.y = pk2(oacc[dt][rg*4+2]*inv, oacc[dt][rg*4+3]*inv);
                *(uint2*)(op + d0) = val;
            }
        }
}

// ---------------- launcher ----------------
extern "C" void kernel_launch(void* const* d_in, const int* in_sizes, int n_in,
                              void* d_out, int out_size, void* d_ws, size_t ws_size,
                              hipStream_t stream) {
    const float* x      = (const float*)d_in[0];
    const float* mask   = (const float*)d_in[1];
    const float* emb_w1 = (const float*)d_in[2];
    const float* emb_b1 = (const float*)d_in[3];
    const float* emb_w2 = (const float*)d_in[4];
    const float* emb_b2 = (const float*)d_in[5];
    const float* qkv_w  = (const float*)d_in[6];
    const float* proj_w = (const float*)d_in[7];
    const float* proj_b = (const float*)d_in[8];
    const float* mlp_w1 = (const float*)d_in[9];
    const float* mlp_b1 = (const float*)d_in[10];
    const float* mlp_w2 = (const float*)d_in[11];
    const float* mlp_b2 = (const float*)d_in[12];
    const float* ln1_s  = (const float*)d_in[13];
    const float* ln1_b  = (const float*)d_in[14];
    const float* ln2_s  = (const float*)d_in[15];
    const float* ln2_b  = (const float*)d_in[16];

    const size_t S1 = (size_t)NTOK*CH;
    float*  h     = (float*)d_ws;               // fp32 [NTOK][CH]
    ushort* hbf   = (ushort*)(h + S1);          // bf16 shadow of h
    ushort* qkvbf = hbf + S1;                   // bf16 [NTOK][C3] (rope'd Q/K)
    ushort* ybf   = qkvbf + 3*S1;               // embed1 out
    ushort* t2bf  = ybf  + S1;
    ushort* obf   = t2bf + S1;
    ushort* vtbuf = obf  + S1;                  // bf16 [B*H*64][SEQ] transposed V (d padded)
    ushort* wb_emb2 = vtbuf + (size_t)BATCH*NHEAD*64*SEQ;   // 147456 (contiguous w/ next two)
    ushort* wb_proj = wb_emb2 + 147456;
    ushort* wb_m2   = wb_proj + 884736;
    ushort* wqkvp   = wb_m2   + 884736;
    ushort* wm1p    = wqkvp   + 2654208;
    float2* uv_qkv  = (float2*)(wm1p + 884736);
    float2* uv_m1   = uv_qkv + 6912;
    float2* sb      = uv_m1  + 2304;            // 12 x NTOK (sum, sumsq)
    float*  tbl     = (float*)(sb + 12*NTOK);
    const float2* tblc = (const float2*)tbl;

    init_kernel<<<385, 256, 0, stream>>>((float4*)sb, (float2*)tbl);
    f2bf3_kernel<<<1872, 256, 0, stream>>>(emb_w2, proj_w, mlp_w2, wb_emb2);
    prep_kernel<<<1728, 256, 0, stream>>>(qkv_w,  ln1_s, ln1_b, nullptr, C3, wqkvp, uv_qkv);
    prep_kernel<<<576,  256, 0, stream>>>(mlp_w1, ln2_s, ln2_b, mlp_b1,  CH, wm1p,  uv_m1);

    embed1_kernel<<<(NTOK*CH)/256, 256, 0, stream>>>(x, emb_w1, emb_b1, ybf);
    gemm_kernel<false,false,false,false><<<768, 256, 0, stream>>>(ybf, wb_emb2, emb_b2,
            nullptr, nullptr, nullptr, h, hbf, CH, 3, sb, nullptr, nullptr);

    for (int i = 0; i < DEPTH; ++i) {
        // qkv (LN1 folded): Q/K rope'd -> qkvbf ; V -> vtbuf transposed
        gemm_kernel<true,false,false,true><<<2304, 256, 0, stream>>>(hbf,
                wqkvp + (size_t)i*C3*CH, nullptr, uv_qkv + i*C3, sb + (size_t)(2*i)*NTOK,
                nullptr, nullptr, qkvbf, C3, 9, nullptr, vtbuf, tblc);
        attn_kernel<<<BATCH*NHEAD, 512, 0, stream>>>(qkvbf, vtbuf, mask, obf);
        // proj + resid ; stats -> sb[2i+1]
        gemm_kernel<false,false,true,false><<<768, 256, 0, stream>>>(obf,
                wb_proj + (size_t)i*CH*CH, proj_b + i*CH, nullptr, nullptr,
                h, h, hbf, CH, 3, sb + (size_t)(2*i+1)*NTOK, nullptr, nullptr);
        // mlp1 (LN2 folded, relu)
        gemm_kernel<true,true,false,false><<<768, 256, 0, stream>>>(hbf,
                wm1p + (size_t)i*CH*CH, nullptr, uv_m1 + i*CH, sb + (size_t)(2*i+1)*NTOK,
                nullptr, nullptr, t2bf, CH, 3, nullptr, nullptr, nullptr);
        // mlp2 + resid ; stats -> sb[2i+2] (skip last)
        gemm_kernel<false,false,true,false><<<768, 256, 0, stream>>>(t2bf,
                wb_m2 + (size_t)i*CH*CH, mlp_b2 + i*CH, nullptr, nullptr,
                h, h, hbf, CH, 3, (i < DEPTH-1) ? (sb + (size_t)(2*i+2)*NTOK) : nullptr,
                nullptr, nullptr);
    }
    hipMemcpyAsync(d_out, h, S1*sizeof(float), hipMemcpyDeviceToDevice, stream);
}